// Round 15
// baseline (108.928 us; speedup 1.0000x reference)
//
#include <hip/hip_runtime.h>
#include <hip/hip_bf16.h>

// Problem constants: B=16, N=16384, D=256, grid 128x128, K=3 depthwise, GELU.
// coords = per-batch permutation of all cells -> collision-free, min=(0,0).
//
// R15 = R14 with 16x8 tiles (2048 blocks). R14 evidence: compiler clamps to
// the 6-waves/SIMD VGPR tier (84) but the 1024-block grid supplies only
// 4 waves/SIMD -> latency-bound at 3.9 TB/s eff. Halving tile height halves
// the per-wave register window (4-row column window) and doubles the grid,
// letting 6 blocks/CU actually materialize. Prefetch stays sched_barrier'd.
#define BB 16
#define NN 16384
#define GW 128
#define TSX 16           // tile width  (columns)
#define TSY 8            // tile height (rows)
#define HSX 18           // halo width
#define HSY 10           // halo height

typedef float f32x4 __attribute__((ext_vector_type(4)));

// ---------------------------------------------------------------------------
// Kernel 1: inverse permutation + zero-row init
// ---------------------------------------------------------------------------
__global__ __launch_bounds__(256) void build_inv_kernel(
    const int* __restrict__ coords, int* __restrict__ inv,
    float* __restrict__ zrow) {
  int i = blockIdx.x * blockDim.x + threadIdx.x;   // 0 .. B*N-1
  int b = i >> 14;
  int gx = coords[2 * (size_t)i];
  int gy = coords[2 * (size_t)i + 1];
  inv[(b << 14) + (gy << 7) + gx] = i & (NN - 1);
  if (blockIdx.x == 0) zrow[threadIdx.x] = 0.0f;   // 256 floats = 1 row
}

__device__ __forceinline__ float gelu_fast(float a) {
  // gelu_tanh(a) = a * sigmoid(1.5957691216*(a + 0.044715*a^3))
  const float s = a * a;
  const float t = fmaf(0.044715f * a, s, a);
  const float e = __builtin_amdgcn_exp2f(t * -2.3022083f);
  return a * __builtin_amdgcn_rcpf(1.0f + e);
}

// load halo column j (4 stacked rows r0..r0+3) for this lane's 4 channels
#define LCOL(j, col)                                                      \
  _Pragma("unroll") for (int r4 = 0; r4 < 4; ++r4) {                      \
    const int n_ = __builtin_amdgcn_readfirstlane(s_inv[r0 + r4][j]);     \
    const float* p_ = (n_ >= 0) ? xb + ((size_t)n_ << 8) : zrow;          \
    col[r4] = *(const f32x4*)(p_ + c4);                                   \
  }

// ---------------------------------------------------------------------------
// Kernel 2: 16x8 tile; wave w -> rows 2w..2w+1; lane -> 4 channels (f32x4).
// ---------------------------------------------------------------------------
__global__ __launch_bounds__(256) void mixer_kernel(
    const float* __restrict__ x, const float* __restrict__ cw,
    const float* __restrict__ cb, const int* __restrict__ inv,
    const float* __restrict__ zrow, float* __restrict__ out) {
  __shared__ int s_inv[HSY][HSX];

  const int id = blockIdx.x;               // 2048 blocks
  const int rem = id >> 3;                 // 0..255
  const int b = ((id & 7) << 1) + (rem >> 7);   // XCD-swizzled batch
  const int tile = rem & 127;              // 128 tiles/batch (16 rows x 8)
  const int gy0 = (tile >> 3) * TSY;
  const int gx0 = (tile & 7) * TSX;

  const int tid = threadIdx.x;
  const int lane = tid & 63;
  const int wv = tid >> 6;
  const int c4 = lane << 2;                // first channel of this lane

  if (tid < HSY * HSX) {
    const int wy = tid / HSX, wx = tid - wy * HSX;
    const int gy = gy0 - 1 + wy, gx = gx0 - 1 + wx;
    int nv = -1;
    if ((unsigned)gy < (unsigned)GW && (unsigned)gx < (unsigned)GW)
      nv = inv[(b << 14) + (gy << 7) + gx];
    s_inv[wy][wx] = nv;
  }

  // per-lane weights/bias for channels c4..c4+3
  f32x4 wq[9], bq;
#pragma unroll
  for (int cc = 0; cc < 4; ++cc) {
    bq[cc] = cb[c4 + cc];
#pragma unroll
    for (int j = 0; j < 9; ++j) wq[j][cc] = cw[(c4 + cc) * 9 + j];
  }
  __syncthreads();

  const float* __restrict__ xb = x + ((size_t)b << 22);
  float* __restrict__ ob = out + ((size_t)b << 22);
  const int r0 = wv << 1;                  // halo row base of this wave

  // sliding 3-column window + 1 prefetch column (all static after unroll)
  f32x4 cA[4], cB[4], cC[4], cD[4];
  LCOL(0, cA)
  LCOL(1, cB)
  LCOL(2, cC)
#pragma unroll
  for (int j = 2; j < HSX; ++j) {
    // A) prefetch next column's 4 rows -- pinned before compute
    if (j + 1 < HSX) { LCOL(j + 1, cD) }
    __builtin_amdgcn_sched_barrier(0);

    // B) compute outputs: tile rows r0..r0+1, tile column j-2
#pragma unroll
    for (int rr = 0; rr < 2; ++rr) {
      f32x4 a = bq;
      a += wq[0] * cA[rr];
      a += wq[1] * cB[rr];
      a += wq[2] * cC[rr];
      a += wq[3] * cA[rr + 1];
      a += wq[4] * cB[rr + 1];
      a += wq[5] * cC[rr + 1];
      a += wq[6] * cA[rr + 2];
      a += wq[7] * cB[rr + 2];
      a += wq[8] * cC[rr + 2];
      f32x4 res;
#pragma unroll
      for (int cc = 0; cc < 4; ++cc)
        res[cc] = cB[rr + 1][cc] + gelu_fast(a[cc]);
      const int n = __builtin_amdgcn_readfirstlane(s_inv[r0 + rr + 1][j - 1]);
      __builtin_nontemporal_store(res, (f32x4*)(ob + ((size_t)n << 8) + c4));
    }
    // C) rotate window (SSA renames after full unroll)
#pragma unroll
    for (int r4 = 0; r4 < 4; ++r4) {
      cA[r4] = cB[r4];
      cB[r4] = cC[r4];
      cC[r4] = cD[r4];
    }
  }
}

// ---------------------------------------------------------------------------
extern "C" void kernel_launch(void* const* d_in, const int* in_sizes, int n_in,
                              void* d_out, int out_size, void* d_ws,
                              size_t ws_size, hipStream_t stream) {
  const float* x = (const float*)d_in[0];
  const int* coords = (const int*)d_in[1];
  const float* cw = (const float*)d_in[2];
  const float* cb = (const float*)d_in[3];
  float* out = (float*)d_out;
  int* inv = (int*)d_ws;                        // B*N ints = 1 MiB
  float* zrow = (float*)d_ws + (size_t)BB * NN; // 256 floats after inv

  {
    dim3 grid((BB * NN) / 256), block(256);
    build_inv_kernel<<<grid, block, 0, stream>>>(coords, inv, zrow);
  }
  {
    dim3 grid(BB * (GW / TSY) * (GW / TSX)), block(256);   // 2048 blocks
    mixer_kernel<<<grid, block, 0, stream>>>(x, cw, cb, inv, zrow, out);
  }
}